// Round 3
// baseline (276.170 us; speedup 1.0000x reference)
//
#include <hip/hip_runtime.h>
#include <hip/hip_bf16.h>

// AFT-Full on gfx950 — fragment-linear + MX-fp8 GEMM2 + XCD-slab scheduling.
// ew = exp(wbias) = 1 + E, |E|<=0.039: num = colsumZ + E@eKV, den = colsumK + E@eK.
// colsums exact (f32 atomics in GEMM1 epilogue); correction GEMM in fp8 e4m3 via
// mfma_scale_f32_32x32x64_f8f6f4 (scales pinned 1.0; static E*32, Z/4, /8 undo).
// Round-11: intra-wave software pipeline.  Rounds 9/10 serialized {ds_read drain ->
// MFMA} per phase (measured phase ~1840 cyc vs MFMA 512 -> MfmaUtil capped ~30%).
// New: 256-thr / 4-wave, block 256x128, wave 128x64 (acc[4][2]), ring-4 LDS
// (4 x 24KB = 96KB).  Per phase g: {read ks1 frags || stage slot g+3 (6 loads) ->
// 8 MFMA ks0 (frags preloaded LAST phase) -> read phase-g+1 ks0 frags from slot
// g+1 -> 8 MFMA ks1 -> vmcnt(6) -> barrier}.  LDS pipe (576 cyc/CU/phase) now runs
// UNDER the MFMA pipe (512 cyc) instead of in series.  vmcnt(6) at end of g drains
// stage(g-1) -> slot g+2 ready for phase g+1's pre-read; never drains to 0 in loop.

#define AS1(p) ((const __attribute__((address_space(1))) void*)(p))
#define AS3(p) ((__attribute__((address_space(3))) void*)(p))

typedef _Float16 half8 __attribute__((ext_vector_type(8)));
typedef _Float16 half4v __attribute__((ext_vector_type(4)));
typedef float floatx16 __attribute__((ext_vector_type(16)));
typedef int intx4 __attribute__((ext_vector_type(4)));
typedef int intx8 __attribute__((ext_vector_type(8)));

// f16 fragment-linear 128x64 tile (8192 halfs): [r>>5][k>>4][(k>>3)&1][r&31][k&7]
__device__ __forceinline__ long frag_off(int r, int k) {
  return (long)(((((r >> 5) * 4 + (k >> 4)) * 2 + ((k >> 3) & 1)) * 32 + (r & 31)) * 8 + (k & 7));
}
// fp8 fragment-linear 128x128 tile (16384 B)
__device__ __forceinline__ long off8(int r, int k) {
  return (long)((((((r >> 5) * 2 + ((k >> 6) & 1)) * 2 + ((k >> 4) & 1)) * 2 + ((k >> 5) & 1)) * 32 +
                 (r & 31)) * 16 + (k & 15));
}

// ---------------- prep_all ----------------
// blocks [0,1024): x -> f16 frag tiles; [1024,1536): W -> f16 tiles via LDS;
// [1536,1792): (exp(wbias)-1)*32 -> fp8 frag tiles
__global__ __launch_bounds__(256) void prep_all(
    const float* __restrict__ x, const float* __restrict__ wb, const float* __restrict__ Wq,
    const float* __restrict__ Wk, const float* __restrict__ Wv, const float* __restrict__ Wo,
    _Float16* __restrict__ x_h, char* __restrict__ E8, _Float16* __restrict__ WqkvT,
    _Float16* __restrict__ WoT) {
  __shared__ _Float16 lds[64 * 132];
  const int bid = blockIdx.x;
  const int tid = threadIdx.x;

  if (bid < 1024) {  // x -> f16 tiles
    const int tm = bid >> 4, tk = bid & 15;
    const long tbase = (long)bid * 8192;
#pragma unroll
    for (int p = 0; p < 4; ++p) {
      const int s = p * 256 + tid;
      const int r = ((s >> 8) << 5) + (s & 31);
      const int k = ((s >> 6) & 3) * 16 + ((s >> 5) & 1) * 8;
      const float* sp = x + (long)(tm * 128 + r) * 1024 + tk * 64 + k;
      const float4 v0 = *(const float4*)sp;
      const float4 v1 = *(const float4*)(sp + 4);
      half8 h;
      h[0] = (_Float16)v0.x; h[1] = (_Float16)v0.y; h[2] = (_Float16)v0.z; h[3] = (_Float16)v0.w;
      h[4] = (_Float16)v1.x; h[5] = (_Float16)v1.y; h[6] = (_Float16)v1.z; h[7] = (_Float16)v1.w;
      *(half8*)(x_h + tbase + (long)s * 8) = h;
    }
    return;
  }

  if (bid >= 1536) {  // E8: (exp(wb)-1)*32 -> fp8 frag tiles
    const int e = bid - 1536;
    const int tt = e >> 4, ts = e & 15;
    char* dst = E8 + (long)e * 16384;
#pragma unroll
    for (int p = 0; p < 16; ++p) {
      const int idx = p * 256 + tid;
      const int r = idx >> 5, k = (idx & 31) * 4;
      const float4 v = *(const float4*)(wb + (long)(tt * 128 + r) * 2048 + ts * 128 + k);
      const float e0 = (__expf(v.x) - 1.0f) * 32.0f, e1 = (__expf(v.y) - 1.0f) * 32.0f;
      const float e2 = (__expf(v.z) - 1.0f) * 32.0f, e3 = (__expf(v.w) - 1.0f) * 32.0f;
      int pk = __builtin_amdgcn_cvt_pk_fp8_f32(e0, e1, 0, false);
      pk = __builtin_amdgcn_cvt_pk_fp8_f32(e2, e3, pk, true);
      *(int*)(dst + off8(r, k)) = pk;
    }
    return;
  }

  // ---- weight tiler (f16) ----
  const int b2 = bid - 1024;
  const float* src0;
  const float* src1 = nullptr;
  _Float16* dst;
  int tn, tk, cb = 0;
  if (b2 < 128) {
    tn = b2 >> 4; tk = b2 & 15; src0 = Wq; dst = WqkvT;
  } else if (b2 < 384) {
    const int t = b2 - 128;
    tn = 8 + (t >> 4); tk = t & 15; cb = (tn - 8) * 64; src0 = Wk; src1 = Wv; dst = WqkvT;
  } else {
    const int t = b2 - 384;
    tn = t >> 4; tk = t & 15; src0 = Wo; dst = WoT;
  }
  if (!src1) {
#pragma unroll
    for (int p = 0; p < 8; ++p) {
      const int kl = p * 8 + (tid >> 5);
      const int cl = (tid & 31) * 4;
      const float4 v = *(const float4*)(src0 + (long)(tk * 64 + kl) * 1024 + tn * 128 + cl);
      half4v h;
      h[0] = (_Float16)v.x; h[1] = (_Float16)v.y; h[2] = (_Float16)v.z; h[3] = (_Float16)v.w;
      *(half4v*)(lds + kl * 132 + cl) = h;
    }
  } else {
#pragma unroll
    for (int m = 0; m < 2; ++m) {
      const float* s = m ? src1 : src0;
      const int rb = m ? 32 : 0;
#pragma unroll
      for (int p = 0; p < 4; ++p) {
        const int kl = p * 16 + (tid >> 4);
        const int cl = (tid & 15) * 4;
        const int rl = (cl >> 5) * 64 + rb + (cl & 31);
        const float4 v = *(const float4*)(s + (long)(tk * 64 + kl) * 1024 + cb + cl);
        half4v h;
        h[0] = (_Float16)v.x; h[1] = (_Float16)v.y; h[2] = (_Float16)v.z; h[3] = (_Float16)v.w;
        *(half4v*)(lds + kl * 132 + rl) = h;
      }
    }
  }
  __syncthreads();
  const long tbase = (long)(tn * 16 + tk) * 8192;
#pragma unroll
  for (int p = 0; p < 4; ++p) {
    const int s = p * 256 + tid;
    const int r = ((s >> 8) << 5) + (s & 31);
    const int kl = ((s >> 6) & 3) * 16 + ((s >> 5) & 1) * 8;
    half8 h;
#pragma unroll
    for (int j = 0; j < 8; ++j) h[j] = lds[(kl + j) * 132 + r];
    *(half8*)(dst + tbase + (long)s * 8) = h;
  }
}

// ---------------- f16 GEMM, 256x128 tile, 4 waves (128x64 each), ring-4, pipelined ----------------
// K = 1024 = 32 K-halves of 32.  Slot = A 16KB (two 128-row sub-tiles) + B 8KB.
// Per phase g (on entry afc/bfc hold (g,ks0) frags; slot g+1 staged & drained):
//   read (g,ks1) frags [6 ds_read] ; stage K-half g+3 -> slot (g+3)&3 [6 loads] ;
//   8 MFMA ks0 ; read (g+1,ks0) frags from slot (g+1)&3 ; 8 MFMA ks1 ;
//   vmcnt(6) [drains stage(g-1) -> slot g+2 ready] ; barrier.
template <int VM, bool STAGE, bool LOADNEXT>
__device__ __forceinline__ void aft_phase3(
    const int g, _Float16* __restrict__ ring, _Float16* __restrict__ ringB,
    const _Float16* gA0, const _Float16* gA1, const _Float16* gB,
    const int tid, const int lane, const int wm, const int wn,
    half8 (&afc)[4], half8 (&bfc)[2], floatx16 (&acc)[4][2]) {
  const int slot = g & 3, nslot = (g + 1) & 3, sslot = (g + 3) & 3;
  const _Float16* rA = ring + slot * 8192 + (wm >> 7) * 4096 + lane * 8;
  const _Float16* rB = ringB + slot * 4096 + (wn >> 5) * 1024 + lane * 8;
  half8 afn[4], bfn[2];
#pragma unroll
  for (int mf = 0; mf < 4; ++mf) afn[mf] = *(const half8*)(rA + mf * 1024 + 512);
#pragma unroll
  for (int nf = 0; nf < 2; ++nf) bfn[nf] = *(const half8*)(rB + nf * 1024 + 512);
  if (STAGE) {
    const long soff = (long)((g + 3) >> 1) * 8192 + (long)((g + 3) & 1) * 1024;
    _Float16* dA = ring + sslot * 8192 + tid * 8;
    _Float16* dB = ringB + sslot * 4096 + tid * 8;
#pragma unroll
    for (int p = 0; p < 2; ++p) {
      __builtin_amdgcn_global_load_lds(AS1(gA0 + soff + p * 4096), AS3(dA + p * 2048), 16, 0, 0);
      __builtin_amdgcn_global_load_lds(AS1(gA1 + soff + p * 4096), AS3(dA + 4096 + p * 2048), 16, 0, 0);
      __builtin_amdgcn_global_load_lds(AS1(gB + soff + p * 4096), AS3(dB + p * 2048), 16, 0, 0);
    }
  }
  __builtin_amdgcn_s_setprio(1);
#pragma unroll
  for (int mf = 0; mf < 4; ++mf)
#pragma unroll
    for (int nf = 0; nf < 2; ++nf)
      acc[mf][nf] = __builtin_amdgcn_mfma_f32_32x32x16_f16(afc[mf], bfc[nf], acc[mf][nf], 0, 0, 0);
  __builtin_amdgcn_s_setprio(0);
  if (LOADNEXT) {
    const _Float16* rA2 = ring + nslot * 8192 + (wm >> 7) * 4096 + lane * 8;
    const _Float16* rB2 = ringB + nslot * 4096 + (wn >> 5) * 1024 + lane * 8;
#pragma unroll
    for (int mf = 0; mf < 4; ++mf) afc[mf] = *(const half8*)(rA2 + mf * 1024);
#pragma unroll
    for (int nf = 0; nf < 2; ++nf) bfc[nf] = *(const half8*)(rB2 + nf * 1024);
  }
  __builtin_amdgcn_s_setprio(1);
#pragma unroll
  for (int mf = 0; mf < 4; ++mf)
#pragma unroll
    for (int nf = 0; nf < 2; ++nf)
      acc[mf][nf] = __builtin_amdgcn_mfma_f32_32x32x16_f16(afn[mf], bfn[nf], acc[mf][nf], 0, 0, 0);
  __builtin_amdgcn_s_setprio(0);
  if constexpr (VM >= 0) {
    asm volatile("s_waitcnt vmcnt(%0)" ::"i"(VM) : "memory");
    __builtin_amdgcn_s_barrier();
    asm volatile("" ::: "memory");
  }
}

// Block order: XCD x = f&7 owns m-slab [4x, 4x+4) of 256-row tiles, walks n slowly.
// MODE 0 (GEMM1): n0<1024 -> Qsig C-frag sigmoid(+bq); else K/V pair -> Zt8 + colsums.
// MODE 2 (GEMM3): fp32 row-major store + bias0.
template <int MODE>
__global__ __launch_bounds__(256, 1) void gemm_bt2(
    const _Float16* __restrict__ A, const _Float16* __restrict__ Bt, void* __restrict__ Cv,
    const float* __restrict__ bias0, const float* __restrict__ bias1,
    const float* __restrict__ bias2, char* __restrict__ Zt8, float* __restrict__ cs) {
  __shared__ __align__(16) _Float16 ring[49152];  // A: 4x8192 halfs | B: 4x4096 halfs
  _Float16* ringB = ring + 32768;
  const int tid = threadIdx.x;
  const int wid = tid >> 6, lane = tid & 63;
  const int l32 = lane & 31, khalf = lane >> 5;

  const int f = blockIdx.x;
  const int bxs = (f & 7) * 4 + ((f >> 3) & 3);
  const int bys = f >> 5;
  const int m0 = bxs * 256, n0 = bys * 128;
  const int wm = (wid >> 1) * 128, wn = (wid & 1) * 64;

  const long thrOff = (long)(tid >> 7) * 2048 + (tid & 127) * 8;
  const _Float16* gA0 = A + (long)(bxs * 2) * 131072 + thrOff;
  const _Float16* gA1 = gA0 + 131072;
  const _Float16* gB = Bt + (long)bys * 131072 + thrOff;

  // prologue: stage K-halves 0,1,2 into slots 0,1,2 (18 loads); drain slots 0,1
#pragma unroll
  for (int hh = 0; hh < 3; ++hh) {
    const long soff = (long)(hh >> 1) * 8192 + (long)(hh & 1) * 1024;
    _Float16* dA = ring + hh * 8192 + tid * 8;
    _Float16* dB = ringB + hh * 4096 + tid * 8;
#pragma unroll
    for (int p = 0; p < 2; ++p) {
      __builtin_amdgcn_global_load_lds(AS1(gA0 + soff + p * 4096), AS3(dA + p * 2048), 16, 0, 0);
      __builtin_amdgcn_global_load_lds(AS1(gA1 + soff + p * 4096), AS3(dA + 4096 + p * 2048), 16, 0, 0);
      __builtin_amdgcn_global_load_lds(AS1(gB + soff + p * 4096), AS3(dB + p * 2048), 16, 0, 0);
    }
  }
  asm volatile("s_waitcnt vmcnt(6)" ::: "memory");
  __builtin_amdgcn_s_barrier();
  asm volatile("" ::: "memory");

  half8 afc[4], bfc[2];
  {
    const _Float16* rA = ring + (wm >> 7) * 4096 + lane * 8;
    const _Float16* rB = ringB + (wn >> 5) * 1024 + lane * 8;
#pragma unroll
    for (int mf = 0; mf < 4; ++mf) afc[mf] = *(const half8*)(rA + mf * 1024);
#pragma unroll
    for (int nf = 0; nf < 2; ++nf) bfc[nf] = *(const half8*)(rB + nf * 1024);
  }

  floatx16 acc[4][2] = {};
#pragma unroll
  for (int g = 0; g < 29; ++g)
    aft_phase3<6, true, true>(g, ring, ringB, gA0, gA1, gB, tid, lane, wm, wn, afc, bfc, acc);
  aft_phase3<0, false, true>(29, ring, ringB, gA0, gA1, gB, tid, lane, wm, wn, afc, bfc, acc);
  aft_phase3<-1, false, true>(30, ring, ringB, gA0, gA1, gB, tid, lane, wm, wn, afc, bfc, acc);
  aft_phase3<-1, false, false>(31, ring, ringB, gA0, gA1, gB, tid, lane, wm, wn, afc, bfc, acc);

  if (MODE == 0) {
    if (n0 < 1024) {
      _Float16* Qs = (_Float16*)Cv;
#pragma unroll
      for (int mf = 0; mf < 4; ++mf) {
        const long ttile = (m0 + wm + mf * 32) >> 5;
#pragma unroll
        for (int nf = 0; nf < 2; ++nf) {
          const int col = n0 + wn + nf * 32 + l32;
          const float bb = bias0[col];
          const long base = (ttile * 32 + ((n0 + wn) >> 5) + nf) * 1024;
#pragma unroll
          for (int q = 0; q < 4; ++q) {
            half4v o;
#pragma unroll
            for (int rr = 0; rr < 4; ++rr) {
              const float v = acc[mf][nf][q * 4 + rr] + bb;
              o[rr] = (_Float16)(1.0f / (1.0f + __expf(-v)));
            }
            *(half4v*)(Qs + base + q * 256 + lane * 4) = o;
          }
        }
      }
    } else {
      const int b = m0 >> 11;
      const int grp = (n0 - 1024 + wn) >> 6;
      const int ch = grp * 32 + l32;
      const float bkc = bias1[ch], bvc = bias2[ch];
      const int jn = grp * 64 + l32;  // Zt num row; den = +32 (same 128-tile)
      const int tc = ((m0 & 2047) >> 7) + (wm >> 7);
      char* Z8 = Zt8 + (long)b * 4194304 + ((long)(jn >> 7) * 16 + tc) * 16384;
      const int jnl = jn & 127;
      float sk = 0.f, sz = 0.f;
#pragma unroll
      for (int mf = 0; mf < 4; ++mf) {
#pragma unroll
        for (int q = 0; q < 4; ++q) {
          float ekv[4], ekk[4];
#pragma unroll
          for (int rr = 0; rr < 4; ++rr) {
            const float ek = __expf(acc[mf][0][q * 4 + rr] + bkc);
            const float vv = acc[mf][1][q * 4 + rr] + bvc;
            ekk[rr] = ek;
            ekv[rr] = ek * vv;
            sk += ek;
            sz += ek * vv;
          }
          const int sl = mf * 32 + 4 * khalf + 8 * q;  // s within 128-tile (+rr)
          int pn = __builtin_amdgcn_cvt_pk_fp8_f32(ekv[0] * 0.25f, ekv[1] * 0.25f, 0, false);
          pn = __builtin_amdgcn_cvt_pk_fp8_f32(ekv[2] * 0.25f, ekv[3] * 0.25f, pn, true);
          int pd = __builtin_amdgcn_cvt_pk_fp8_f32(ekk[0] * 0.25f, ekk[1] * 0.25f, 0, false);
          pd = __builtin_amdgcn_cvt_pk_fp8_f32(ekk[2] * 0.25f, ekk[3] * 0.25f, pd, true);
          *(int*)(Z8 + off8(jnl, sl)) = pn;
          *(int*)(Z8 + off8(jnl + 32, sl)) = pd;
        }
      }
      atomicAdd(&cs[(long)b * 2048 + ch * 2], sz);
      atomicAdd(&cs[(long)b * 2048 + ch * 2 + 1], sk);
    }
    return;
  }

  // MODE 2: fp32 row-major + bias0
#pragma unroll
  for (int mf = 0; mf < 4; ++mf)
#pragma unroll
    for (int nf = 0; nf < 2; ++nf) {
      const int col = n0 + wn + nf * 32 + l32;
      const float bb = bias0[col];
#pragma unroll
      for (int reg = 0; reg < 16; ++reg) {
        const int row = m0 + wm + mf * 32 + 4 * khalf + 8 * (reg >> 2) + (reg & 3);
        ((float*)Cv)[(long)row * 1024 + col] = acc[mf][nf][reg] + bb;
      }
    }
}

// ---------------- GEMM2: fp8 correction  acc = (E*32) @ (Z/4)^T, BK=128 ----------------
// OutHead = Qsig * (csZ + accn/8) / (csK + accd/8), grid (16,16,4).
__global__ __launch_bounds__(256) void gemm2_fp8(
    const char* __restrict__ E8, const char* __restrict__ Zt8, _Float16* __restrict__ OH,
    const _Float16* __restrict__ Qsig, const float* __restrict__ cs) {
  __shared__ __align__(16) char sA[16384];
  __shared__ __align__(16) char sB[16384];
  const int tid = threadIdx.x;
  const int wave = tid >> 6, lane = tid & 63;
  const int l32 = lane & 31, khalf = lane >> 5;

  const int f = blockIdx.x + 16 * (blockIdx.y + 16 * blockIdx.z);
  const int nid = (f & 7) * 128 + (f >> 3);
  const int bxs = nid & 15, bys = (nid >> 4) & 15, bzs = nid >> 8;

  const int m0 = bxs * 128, n0 = bys * 128;
  const int wm = (wave >> 1) * 64, wn = (wave & 1) * 64;

  const char* At = E8 + (long)bxs * 16 * 16384;
  const char* Bt = Zt8 + (long)bzs * 4194304 + (long)bys * 16 * 16384;

  floatx16 acc[2][2] = {};

  for (int tk = 0; tk < 16; ++tk) {
    const char* As = At + tk * 16384 + wave * 1024 + lane * 16;
    const char* Bs = Bt + tk * 16384 + wave * 1024 + lane * 16;
#pragma unroll
    for (int c = 0; c < 4; ++c) {
      __builtin_amdgcn_global_load_lds(AS1(As + c * 4096), AS3(sA + c * 4096 + wave * 1024), 16, 0, 0);
      __builtin_amdgcn_global_load_lds(AS1(Bs + c * 4096), AS3(sB + c * 4096 + wave * 1024), 16, 0, 0);
    }
    __syncthreads();
#pragma unroll
    for (int ks = 0; ks < 2; ++ks) {
      intx8 a8[2], b8[2];
#pragma unroll
      for (int i = 0; i < 2; ++i) {
        const char* pa = sA + (((wm >> 5) + i) * 2 + ks) * 2048 + khalf * 512 + l32 * 16;
        const intx4 alo = *(const intx4*)pa;
        const intx4 ahi = *(const intx4*)(pa + 1024);
        a8[i] = __builtin_shufflevector(alo, ahi, 0, 1, 2, 3, 4, 5, 6, 7);
        const char* pb = sB + (((wn >> 5) + i) * 2 + ks) * 2048 + khalf * 512 + l32 * 16;
        const intx4 blo = *(const intx4*)pb;
        const intx4 bhi = *(const intx4*)(pb + 1024);
        b8[i] = __builtin_shufflevector(blo, bhi, 0, 1, 2, 3, 4, 5, 6, 7);
      }
#pragma unroll
      for (int mt = 0; mt < 2; ++mt)
#pragma unroll
        for (int nt = 0; nt < 2; ++nt)
          acc[mt][nt] = __builtin_amdgcn_mfma_scale_f32_32x32x64_f8f6f4(
              a8[mt], b8[nt], acc[mt][nt], 0, 0, 0, 127u, 0, 127u);
    }
    __syncthreads();
  }

  const int ch = ((n0 + wn) >> 6) * 32 + l32;
  const float2 c2 = *(const float2*)(cs + (long)bzs * 2048 + ch * 2);  // (csZ, csK)
#pragma unroll
  for (int mt = 0; mt < 2; ++mt) {
    const long ttile = (long)(bzs * 2048 + m0 + wm + mt * 32) >> 5;
    const long qbase = (ttile * 32 + ((n0 + wn) >> 6)) * 1024;
#pragma unroll
    for (int q = 0; q < 4; ++q) {
      const half4v qv = *(const half4v*)(Qsig + qbase + q * 256 + lane * 4);
#pragma unroll
      for (int rr = 0; rr < 4; ++rr) {
        const int reg = q * 4 + rr;
        const float num = c2.x + acc[mt][0][reg] * 0.125f;
        const float den = c2.y + acc[mt][1][reg] * 0.125f;
        const int r = m0 + wm + mt * 32 + 4 * khalf + 8 * q + rr;
        const int R = bzs * 2048 + r;
        const long off = ((long)(R >> 7) * 16 + (ch >> 6)) * 8192 + frag_off(R & 127, ch & 63);
        OH[off] = (_Float16)((float)qv[rr] * num / den);
      }
    }
  }
}

// ---------------- launch ----------------
extern "C" void kernel_launch(void* const* d_in, const int* in_sizes, int n_in, void* d_out,
                              int out_size, void* d_ws, size_t ws_size, hipStream_t stream) {
  const float* x = (const float*)d_in[0];
  const float* Wq = (const float*)d_in[1];
  const float* bq = (const float*)d_in[2];
  const float* Wk = (const float*)d_in[3];
  const float* bk = (const float*)d_in[4];
  const float* Wv = (const float*)d_in[5];
  const float* bv = (const float*)d_in[6];
  const float* Wo = (const float*)d_in[7];
  const float* bo = (const float*)d_in[8];
  const float* wb = (const float*)d_in[9];

  char* ws = (char*)d_ws;
  _Float16* x_h = (_Float16*)(ws + 0);              // 16 MB  (1024 f16 frag tiles)
  _Float16* WqkvT = (_Float16*)(ws + 16777216);     //  6 MB
  _Float16* WoT = (_Float16*)(ws + 23068672);       //  2 MB
  char* E8 = (char*)(ws + 25165824);                //  4 MB  (256 fp8 frag tiles)
  _Float16* Qsig = (_Float16*)(ws + 29360128);      // 16 MB  (C-frag tiles)
  char* Zt8 = (char*)(ws + 46137344);               // 16 MB  (fp8 frag tiles, 4 batches)
  _Float16* OutHead = (_Float16*)(ws + 62914560);   // 16 MB  (f16 frag tiles)
  float* cs = (float*)(ws + 79691776);              // 32 KB  (csZ,csK interleaved)

  hipMemsetAsync(cs, 0, 4 * 2048 * sizeof(float), stream);

  // prep: x tiles + weight tiles + E8 tiles
  prep_all<<<1792, 256, 0, stream>>>(x, wb, Wq, Wk, Wv, Wo, x_h, E8, WqkvT, WoT);

  // GEMM1: x @ [Wq|Wkv]; epilogue -> Qsig (C-frag), Zt8 (fp8), colsum atomics
  gemm_bt2<0><<<768, 256, 0, stream>>>(x_h, WqkvT, Qsig, bq, bk, bv, Zt8, cs);

  // GEMM2 (fp8 correction + rank-1): OutHead = Qsig*(csZ+E@Z)/(csK+E@eK)
  gemm2_fp8<<<dim3(16, 16, 4), 256, 0, stream>>>(E8, Zt8, OutHead, Qsig, cs);

  // GEMM3: out = OutHead @ Wo + bo (fp32)
  gemm_bt2<2><<<256, 256, 0, stream>>>(OutHead, WoT, d_out, bo, nullptr, nullptr, nullptr, nullptr);
}

// Round 5
// 246.750 us; speedup vs baseline: 1.1192x; 1.1192x over previous
//
#include <hip/hip_runtime.h>
#include <hip/hip_bf16.h>

// AFT-Full on gfx950 — fragment-linear + MX-fp8 GEMM2 + XCD-slab scheduling.
// ew = exp(wbias) = 1 + E, |E|<=0.039: num = colsumZ + E@eKV, den = colsumK + E@eK.
// colsums exact (f32 atomics in GEMM1 epilogue); correction GEMM in fp8 e4m3 via
// mfma_scale_f32_32x32x64_f8f6f4 (scales pinned 1.0; static E*32, Z/4, /8 undo).
// Round-13: round-4's GEMM2 failed because its n-grid treated N as 1024; the Zt8
// B-matrix is 2048 wide (num/den interleaved per 64-group).  Rebuilt: 256x256
// block (n in nd-space), 512 thr / 8 waves (4Mx2N, wave 64x128, acc[2][4] with
// (2p,2p+1)=(num,den) pairs), BK=64, ring-3 LDS (3 x (16KB A + 16KB B) = 96KB),
// counted vmcnt(4) (never 0 in main loop), grid 8m x 8n x 4b = 256 = 1.0/CU.
// GEMM1/GEMM3 stay the round-9 512-thread kernels (known good, 69.5 us).

#define AS1(p) ((const __attribute__((address_space(1))) void*)(p))
#define AS3(p) ((__attribute__((address_space(3))) void*)(p))

typedef _Float16 half8 __attribute__((ext_vector_type(8)));
typedef _Float16 half4v __attribute__((ext_vector_type(4)));
typedef float floatx16 __attribute__((ext_vector_type(16)));
typedef int intx4 __attribute__((ext_vector_type(4)));
typedef int intx8 __attribute__((ext_vector_type(8)));

// f16 fragment-linear 128x64 tile (8192 halfs): [r>>5][k>>4][(k>>3)&1][r&31][k&7]
__device__ __forceinline__ long frag_off(int r, int k) {
  return (long)(((((r >> 5) * 4 + (k >> 4)) * 2 + ((k >> 3) & 1)) * 32 + (r & 31)) * 8 + (k & 7));
}
// fp8 fragment-linear 128x128 tile (16384 B)
__device__ __forceinline__ long off8(int r, int k) {
  return (long)((((((r >> 5) * 2 + ((k >> 6) & 1)) * 2 + ((k >> 4) & 1)) * 2 + ((k >> 5) & 1)) * 32 +
                 (r & 31)) * 16 + (k & 15));
}

// ---------------- prep_all ----------------
// blocks [0,1024): x -> f16 frag tiles; [1024,1536): W -> f16 tiles via LDS;
// [1536,1792): (exp(wbias)-1)*32 -> fp8 frag tiles
__global__ __launch_bounds__(256) void prep_all(
    const float* __restrict__ x, const float* __restrict__ wb, const float* __restrict__ Wq,
    const float* __restrict__ Wk, const float* __restrict__ Wv, const float* __restrict__ Wo,
    _Float16* __restrict__ x_h, char* __restrict__ E8, _Float16* __restrict__ WqkvT,
    _Float16* __restrict__ WoT) {
  __shared__ _Float16 lds[64 * 132];
  const int bid = blockIdx.x;
  const int tid = threadIdx.x;

  if (bid < 1024) {  // x -> f16 tiles
    const int tm = bid >> 4, tk = bid & 15;
    const long tbase = (long)bid * 8192;
#pragma unroll
    for (int p = 0; p < 4; ++p) {
      const int s = p * 256 + tid;
      const int r = ((s >> 8) << 5) + (s & 31);
      const int k = ((s >> 6) & 3) * 16 + ((s >> 5) & 1) * 8;
      const float* sp = x + (long)(tm * 128 + r) * 1024 + tk * 64 + k;
      const float4 v0 = *(const float4*)sp;
      const float4 v1 = *(const float4*)(sp + 4);
      half8 h;
      h[0] = (_Float16)v0.x; h[1] = (_Float16)v0.y; h[2] = (_Float16)v0.z; h[3] = (_Float16)v0.w;
      h[4] = (_Float16)v1.x; h[5] = (_Float16)v1.y; h[6] = (_Float16)v1.z; h[7] = (_Float16)v1.w;
      *(half8*)(x_h + tbase + (long)s * 8) = h;
    }
    return;
  }

  if (bid >= 1536) {  // E8: (exp(wb)-1)*32 -> fp8 frag tiles
    const int e = bid - 1536;
    const int tt = e >> 4, ts = e & 15;
    char* dst = E8 + (long)e * 16384;
#pragma unroll
    for (int p = 0; p < 16; ++p) {
      const int idx = p * 256 + tid;
      const int r = idx >> 5, k = (idx & 31) * 4;
      const float4 v = *(const float4*)(wb + (long)(tt * 128 + r) * 2048 + ts * 128 + k);
      const float e0 = (__expf(v.x) - 1.0f) * 32.0f, e1 = (__expf(v.y) - 1.0f) * 32.0f;
      const float e2 = (__expf(v.z) - 1.0f) * 32.0f, e3 = (__expf(v.w) - 1.0f) * 32.0f;
      int pk = __builtin_amdgcn_cvt_pk_fp8_f32(e0, e1, 0, false);
      pk = __builtin_amdgcn_cvt_pk_fp8_f32(e2, e3, pk, true);
      *(int*)(dst + off8(r, k)) = pk;
    }
    return;
  }

  // ---- weight tiler (f16) ----
  const int b2 = bid - 1024;
  const float* src0;
  const float* src1 = nullptr;
  _Float16* dst;
  int tn, tk, cb = 0;
  if (b2 < 128) {
    tn = b2 >> 4; tk = b2 & 15; src0 = Wq; dst = WqkvT;
  } else if (b2 < 384) {
    const int t = b2 - 128;
    tn = 8 + (t >> 4); tk = t & 15; cb = (tn - 8) * 64; src0 = Wk; src1 = Wv; dst = WqkvT;
  } else {
    const int t = b2 - 384;
    tn = t >> 4; tk = t & 15; src0 = Wo; dst = WoT;
  }
  if (!src1) {
#pragma unroll
    for (int p = 0; p < 8; ++p) {
      const int kl = p * 8 + (tid >> 5);
      const int cl = (tid & 31) * 4;
      const float4 v = *(const float4*)(src0 + (long)(tk * 64 + kl) * 1024 + tn * 128 + cl);
      half4v h;
      h[0] = (_Float16)v.x; h[1] = (_Float16)v.y; h[2] = (_Float16)v.z; h[3] = (_Float16)v.w;
      *(half4v*)(lds + kl * 132 + cl) = h;
    }
  } else {
#pragma unroll
    for (int m = 0; m < 2; ++m) {
      const float* s = m ? src1 : src0;
      const int rb = m ? 32 : 0;
#pragma unroll
      for (int p = 0; p < 4; ++p) {
        const int kl = p * 16 + (tid >> 4);
        const int cl = (tid & 15) * 4;
        const int rl = (cl >> 5) * 64 + rb + (cl & 31);
        const float4 v = *(const float4*)(s + (long)(tk * 64 + kl) * 1024 + cb + cl);
        half4v h;
        h[0] = (_Float16)v.x; h[1] = (_Float16)v.y; h[2] = (_Float16)v.z; h[3] = (_Float16)v.w;
        *(half4v*)(lds + kl * 132 + rl) = h;
      }
    }
  }
  __syncthreads();
  const long tbase = (long)(tn * 16 + tk) * 8192;
#pragma unroll
  for (int p = 0; p < 4; ++p) {
    const int s = p * 256 + tid;
    const int r = ((s >> 8) << 5) + (s & 31);
    const int kl = ((s >> 6) & 3) * 16 + ((s >> 5) & 1) * 8;
    half8 h;
#pragma unroll
    for (int j = 0; j < 8; ++j) h[j] = lds[(kl + j) * 132 + r];
    *(half8*)(dst + tbase + (long)s * 8) = h;
  }
}

// ---------------- f16 GEMM (round-9 best): 128x256 tile, 8 waves, 4-slot ring ----------------
// K = 1024 = 32 K-halves of 32.  Ring: A 4 x 8KB slots, B 4 x 16KB.
// Phase g: read slot g&3 -> stage half g+3 into slot (g+3)&3 -> vmcnt(6) -> barrier
// -> 8 MFMA -> barrier.  vmcnt(6) = 2 most recent phases' 3 loads stay in flight.
template <int VM>
__device__ __forceinline__ void aft_phase(int g, const _Float16* __restrict__ Ablk,
                                          const _Float16* __restrict__ Bblk,
                                          _Float16* ring, int tid, int wid, int lane,
                                          int wm, int wn, floatx16 (&acc)[2][2]) {
  const _Float16* slotA = ring + (g & 3) * 4096;
  const _Float16* slotB = ring + 16384 + (g & 3) * 8192;
  half8 af[2][2], bf[2][2];
#pragma unroll
  for (int mt = 0; mt < 2; ++mt)
#pragma unroll
    for (int ks = 0; ks < 2; ++ks)
      af[mt][ks] = *(const half8*)(slotA + (((wm >> 5) + mt) * 2 + ks) * 512 + lane * 8);
#pragma unroll
  for (int nt = 0; nt < 2; ++nt)
#pragma unroll
    for (int ks = 0; ks < 2; ++ks)
      bf[nt][ks] = *(const half8*)(slotB + (((wn >> 5) + nt) * 2 + ks) * 512 + lane * 8);
  const int gs = g + 3;
  if (gs < 32) {
    const int t = gs >> 1;
    const long goff = (long)(tid >> 7) * 2048 + (gs & 1) * 1024 + (tid & 127) * 8;
    _Float16* dA = ring + (gs & 3) * 4096 + wid * 512;
    _Float16* dB = ring + 16384 + (gs & 3) * 8192 + wid * 512;
    __builtin_amdgcn_global_load_lds(AS1(Ablk + (long)t * 8192 + goff), AS3(dA), 16, 0, 0);
    __builtin_amdgcn_global_load_lds(AS1(Bblk + (long)t * 8192 + goff), AS3(dB), 16, 0, 0);
    __builtin_amdgcn_global_load_lds(AS1(Bblk + (long)(16 + t) * 8192 + goff), AS3(dB + 4096),
                                     16, 0, 0);
  }
  asm volatile("s_waitcnt vmcnt(%0)" ::"i"(VM) : "memory");
  __builtin_amdgcn_s_barrier();
  asm volatile("s_waitcnt lgkmcnt(0)" ::: "memory");
  __builtin_amdgcn_s_setprio(1);
#pragma unroll
  for (int ks = 0; ks < 2; ++ks)
#pragma unroll
    for (int mt = 0; mt < 2; ++mt)
#pragma unroll
      for (int nt = 0; nt < 2; ++nt)
        acc[mt][nt] =
            __builtin_amdgcn_mfma_f32_32x32x16_f16(af[mt][ks], bf[nt][ks], acc[mt][nt], 0, 0, 0);
  __builtin_amdgcn_s_setprio(0);
  __builtin_amdgcn_s_barrier();
  asm volatile("" ::: "memory");
}

// Block order: XCD x = f&7 owns m-slab [8x, 8x+8) of 128-row tiles, walks n slowly.
// MODE 0 (GEMM1): n0<1024 -> Qsig C-frag sigmoid(+bq); else K/V pair -> Zt8 + colsums.
// MODE 2 (GEMM3): fp32 row-major store + bias0.
template <int MODE>
__global__ __launch_bounds__(512, 2) void gemm_bt2(
    const _Float16* __restrict__ A, const _Float16* __restrict__ Bt, void* __restrict__ Cv,
    const float* __restrict__ bias0, const float* __restrict__ bias1,
    const float* __restrict__ bias2, char* __restrict__ Zt8, float* __restrict__ cs) {
  __shared__ __align__(16) _Float16 ring[49152];  // A ring 32KB | B ring 64KB
  const int tid = threadIdx.x;
  const int wid = tid >> 6, lane = tid & 63;
  const int l32 = lane & 31, khalf = lane >> 5;

  const int f = blockIdx.x;
  const int j = f >> 3;
  const int bxs = (f & 7) * 8 + (j & 7);
  const int bys = j >> 3;
  const int m0 = bxs * 128, n0 = bys * 256;
  const int wm = (wid >> 2) * 64, wn = (wid & 3) * 64;

  const _Float16* Ablk = A + (long)bxs * 131072;          // 16 tiles * 8192
  const _Float16* Bblk = Bt + (long)(bys * 2) * 131072;   // 2 consecutive 128-col tiles

  // prologue: stage K-halves 0,1,2 (9 loads), drain oldest 3 -> half 0 ready
#pragma unroll
  for (int g0 = 0; g0 < 3; ++g0) {
    const int t = g0 >> 1;
    const long goff = (long)(tid >> 7) * 2048 + (g0 & 1) * 1024 + (tid & 127) * 8;
    __builtin_amdgcn_global_load_lds(AS1(Ablk + (long)t * 8192 + goff),
                                     AS3(ring + g0 * 4096 + wid * 512), 16, 0, 0);
    __builtin_amdgcn_global_load_lds(AS1(Bblk + (long)t * 8192 + goff),
                                     AS3(ring + 16384 + g0 * 8192 + wid * 512), 16, 0, 0);
    __builtin_amdgcn_global_load_lds(AS1(Bblk + (long)(16 + t) * 8192 + goff),
                                     AS3(ring + 16384 + g0 * 8192 + 4096 + wid * 512), 16, 0, 0);
  }
  asm volatile("s_waitcnt vmcnt(6)" ::: "memory");
  __builtin_amdgcn_s_barrier();
  asm volatile("" ::: "memory");

  floatx16 acc[2][2] = {};
#pragma unroll 1
  for (int gb = 0; gb < 28; gb += 4) {
    aft_phase<6>(gb + 0, Ablk, Bblk, ring, tid, wid, lane, wm, wn, acc);
    aft_phase<6>(gb + 1, Ablk, Bblk, ring, tid, wid, lane, wm, wn, acc);
    aft_phase<6>(gb + 2, Ablk, Bblk, ring, tid, wid, lane, wm, wn, acc);
    aft_phase<6>(gb + 3, Ablk, Bblk, ring, tid, wid, lane, wm, wn, acc);
  }
  aft_phase<6>(28, Ablk, Bblk, ring, tid, wid, lane, wm, wn, acc);
  aft_phase<3>(29, Ablk, Bblk, ring, tid, wid, lane, wm, wn, acc);
  aft_phase<0>(30, Ablk, Bblk, ring, tid, wid, lane, wm, wn, acc);
  aft_phase<0>(31, Ablk, Bblk, ring, tid, wid, lane, wm, wn, acc);

  if (MODE == 0) {
    if (n0 < 1024) {
      _Float16* Qs = (_Float16*)Cv;
#pragma unroll
      for (int mt = 0; mt < 2; ++mt) {
        const long ttile = (m0 + wm + mt * 32) >> 5;
#pragma unroll
        for (int nt = 0; nt < 2; ++nt) {
          const int col = n0 + wn + nt * 32 + l32;
          const float bb = bias0[col];
          const long base = (ttile * 32 + (((n0 + wn) >> 5) + nt)) * 1024;
#pragma unroll
          for (int q = 0; q < 4; ++q) {
            half4v o;
#pragma unroll
            for (int rr = 0; rr < 4; ++rr) {
              const float v = acc[mt][nt][q * 4 + rr] + bb;
              o[rr] = (_Float16)(1.0f / (1.0f + __expf(-v)));
            }
            *(half4v*)(Qs + base + q * 256 + lane * 4) = o;
          }
        }
      }
    } else {
      const int grp = (n0 - 1024 + wn) >> 6;  // 32-channel group
      const int ch = grp * 32 + l32;
      const float bkc = bias1[ch], bvc = bias2[ch];
      const int jn = grp * 64 + l32;          // Zt num row; den = +32 (same 128-tile)
      const int b = m0 >> 11;
      char* Z8 = Zt8 + (long)b * 4194304 +
                 ((long)(jn >> 7) * 16 + ((m0 & 2047) >> 7)) * 16384;
      const int jnl = jn & 127;
      float sk = 0.f, sz = 0.f;
#pragma unroll
      for (int mt = 0; mt < 2; ++mt) {
#pragma unroll
        for (int q = 0; q < 4; ++q) {
          float ekv[4], ekk[4];
#pragma unroll
          for (int rr = 0; rr < 4; ++rr) {
            const float ek = __expf(acc[mt][0][q * 4 + rr] + bkc);
            const float vv = acc[mt][1][q * 4 + rr] + bvc;
            ekk[rr] = ek;
            ekv[rr] = ek * vv;
            sk += ek;
            sz += ek * vv;
          }
          const int sl = wm + mt * 32 + 4 * khalf + 8 * q;  // s within tile (+rr)
          int pn = __builtin_amdgcn_cvt_pk_fp8_f32(ekv[0] * 0.25f, ekv[1] * 0.25f, 0, false);
          pn = __builtin_amdgcn_cvt_pk_fp8_f32(ekv[2] * 0.25f, ekv[3] * 0.25f, pn, true);
          int pd = __builtin_amdgcn_cvt_pk_fp8_f32(ekk[0] * 0.25f, ekk[1] * 0.25f, 0, false);
          pd = __builtin_amdgcn_cvt_pk_fp8_f32(ekk[2] * 0.25f, ekk[3] * 0.25f, pd, true);
          *(int*)(Z8 + off8(jnl, sl)) = pn;
          *(int*)(Z8 + off8(jnl + 32, sl)) = pd;
        }
      }
      atomicAdd(&cs[(long)b * 2048 + ch * 2], sz);
      atomicAdd(&cs[(long)b * 2048 + ch * 2 + 1], sk);
    }
    return;
  }

  // MODE 2: fp32 row-major + bias0
#pragma unroll
  for (int mt = 0; mt < 2; ++mt)
#pragma unroll
    for (int nt = 0; nt < 2; ++nt) {
      const int col = n0 + wn + nt * 32 + l32;
      const float bb = bias0[col];
#pragma unroll
      for (int reg = 0; reg < 16; ++reg) {
        const int row = m0 + wm + mt * 32 + 4 * khalf + 8 * (reg >> 2) + (reg & 3);
        ((float*)Cv)[(long)row * 1024 + col] = acc[mt][nt][reg] + bb;
      }
    }
}

// ---------------- GEMM2: fp8 correction  acc = (E*32) @ (Z/4)^T ----------------
// N-dim = 2048 (num/den interleaved per 64-group).  Block 256 rows x 256 nd-cols,
// 512 thr / 8 waves (4Mx2N, wave 64x128, acc[2][4]); K=2048 = 32 slices of 64;
// ring-3 LDS: slot = A 16KB (2 strips x 4 chunks of 2048B) + B 16KB; 96KB total.
// Phase g: read slot g%3 -> stage slice g+2 into slot (g+2)%3 (4 loads/thread) ->
// vmcnt(4) -> barrier -> lgkmcnt(0) -> 8 mfma_scale -> barrier.
// Slice (t=ks>>1, kh=ks&1) chunk g: global t*16384 + g*4096 + kh*2048 + [0,2048)
// (off8 strides); chunk interior already in fragment order.
// OutHead = Qsig * (csZ + accn/8) / (csK + accd/8).  Grid 8m x 8n x 4b = 256, 1/CU.
template <int VM, bool STAGE, int SLOT>
__device__ __forceinline__ void g2_phase(int g, char* __restrict__ ringA, char* __restrict__ ringB,
                                         const char* At0, const char* At1,
                                         const char* Bt0, const char* Bt1,
                                         int tid, int lane, int wm, int wn,
                                         floatx16 (&acc)[2][4]) {
  const int l32 = lane & 31, khalf = lane >> 5;
  intx8 a8[2], b8[4];
#pragma unroll
  for (int mt = 0; mt < 2; ++mt) {
    const int G = (wm >> 5) + mt;  // 0..7 over 256 rows
    const char* pa = ringA + SLOT * 16384 + (G >> 2) * 8192 + (G & 3) * 2048 + khalf * 512 + l32 * 16;
    const intx4 alo = *(const intx4*)pa;
    const intx4 ahi = *(const intx4*)(pa + 1024);
    a8[mt] = __builtin_shufflevector(alo, ahi, 0, 1, 2, 3, 4, 5, 6, 7);
  }
#pragma unroll
  for (int nt = 0; nt < 4; ++nt) {
    const int Gn = (wn >> 5) + nt;  // 0..7 over 256 nd-rows
    const char* pb = ringB + SLOT * 16384 + (Gn >> 2) * 8192 + (Gn & 3) * 2048 + khalf * 512 + l32 * 16;
    const intx4 blo = *(const intx4*)pb;
    const intx4 bhi = *(const intx4*)(pb + 1024);
    b8[nt] = __builtin_shufflevector(blo, bhi, 0, 1, 2, 3, 4, 5, 6, 7);
  }
  if (STAGE) {
    const int ks = g + 2;  // slice 2..31
    constexpr int SS = (SLOT + 2) % 3;
    const long gsrc = (long)(ks >> 1) * 16384 + (long)(tid >> 7) * 4096 + (long)(ks & 1) * 2048 +
                      (tid & 127) * 16;
    char* dA = ringA + SS * 16384 + tid * 16;
    char* dB = ringB + SS * 16384 + tid * 16;
    __builtin_amdgcn_global_load_lds(AS1(At0 + gsrc), AS3(dA), 16, 0, 0);
    __builtin_amdgcn_global_load_lds(AS1(At1 + gsrc), AS3(dA + 8192), 16, 0, 0);
    __builtin_amdgcn_global_load_lds(AS1(Bt0 + gsrc), AS3(dB), 16, 0, 0);
    __builtin_amdgcn_global_load_lds(AS1(Bt1 + gsrc), AS3(dB + 8192), 16, 0, 0);
  }
  if constexpr (VM >= 0) {
    asm volatile("s_waitcnt vmcnt(%0)" ::"i"(VM) : "memory");
    __builtin_amdgcn_s_barrier();
  }
  asm volatile("s_waitcnt lgkmcnt(0)" ::: "memory");
  __builtin_amdgcn_s_setprio(1);
#pragma unroll
  for (int mt = 0; mt < 2; ++mt)
#pragma unroll
    for (int nt = 0; nt < 4; ++nt)
      acc[mt][nt] = __builtin_amdgcn_mfma_scale_f32_32x32x64_f8f6f4(
          a8[mt], b8[nt], acc[mt][nt], 0, 0, 0, 127u, 0, 127u);
  __builtin_amdgcn_s_setprio(0);
  if constexpr (VM >= 0) {
    __builtin_amdgcn_s_barrier();
    asm volatile("" ::: "memory");
  }
}

__global__ __launch_bounds__(512, 1) void gemm2_fp8(
    const char* __restrict__ E8, const char* __restrict__ Zt8, _Float16* __restrict__ OH,
    const _Float16* __restrict__ Qsig, const float* __restrict__ cs) {
  __shared__ __align__(16) char ring[98304];  // A: 3x16KB | B: 3x16KB
  char* ringA = ring;
  char* ringB = ring + 49152;
  const int tid = threadIdx.x;
  const int wid = tid >> 6, lane = tid & 63;
  const int l32 = lane & 31, khalf = lane >> 5;

  const int f = blockIdx.x;
  const int bxs = f & 7;            // m-tile (256 T-rows) -> XCD affinity
  const int bys = (f >> 3) & 7;     // n-tile (256 nd-cols of 2048)
  const int bzs = f >> 6;           // batch
  const int m0 = bxs * 256;
  const int wm = (wid >> 1) * 64, wn = (wid & 1) * 128;

  const char* At0 = E8 + (long)(bxs * 2) * 262144;   // strip = 16 k-tiles * 16384
  const char* At1 = At0 + 262144;
  const char* Bt0 = Zt8 + (long)bzs * 4194304 + (long)(bys * 2) * 262144;
  const char* Bt1 = Bt0 + 262144;

  // prologue: stage slices 0 -> slot 0, 1 -> slot 1 (8 loads); drain oldest 4
#pragma unroll
  for (int ks = 0; ks < 2; ++ks) {
    const long gsrc = (long)(tid >> 7) * 4096 + (long)(ks & 1) * 2048 + (tid & 127) * 16;
    char* dA = ringA + ks * 16384 + tid * 16;
    char* dB = ringB + ks * 16384 + tid * 16;
    __builtin_amdgcn_global_load_lds(AS1(At0 + gsrc), AS3(dA), 16, 0, 0);
    __builtin_amdgcn_global_load_lds(AS1(At1 + gsrc), AS3(dA + 8192), 16, 0, 0);
    __builtin_amdgcn_global_load_lds(AS1(Bt0 + gsrc), AS3(dB), 16, 0, 0);
    __builtin_amdgcn_global_load_lds(AS1(Bt1 + gsrc), AS3(dB + 8192), 16, 0, 0);
  }
  asm volatile("s_waitcnt vmcnt(4)" ::: "memory");
  __builtin_amdgcn_s_barrier();
  asm volatile("" ::: "memory");

  floatx16 acc[2][4] = {};
#pragma unroll 1
  for (int gb = 0; gb < 30; gb += 3) {
    g2_phase<4, true, 0>(gb + 0, ringA, ringB, At0, At1, Bt0, Bt1, tid, lane, wm, wn, acc);
    g2_phase<4, true, 1>(gb + 1, ringA, ringB, At0, At1, Bt0, Bt1, tid, lane, wm, wn, acc);
    g2_phase<4, true, 2>(gb + 2, ringA, ringB, At0, At1, Bt0, Bt1, tid, lane, wm, wn, acc);
  }
  g2_phase<0, false, 0>(30, ringA, ringB, At0, At1, Bt0, Bt1, tid, lane, wm, wn, acc);
  g2_phase<-1, false, 1>(31, ringA, ringB, At0, At1, Bt0, Bt1, tid, lane, wm, wn, acc);

  // epilogue: pairs (2p, 2p+1) = (num, den) of channel (bys*4 + wn/64 + p)*32 + l32
  const int g32b = bys * 4 + (wn >> 6);
#pragma unroll
  for (int mt = 0; mt < 2; ++mt) {
    const long ttile = (long)(bzs * 2048 + m0 + wm + mt * 32) >> 5;
#pragma unroll
    for (int p = 0; p < 2; ++p) {
      const int g32 = g32b + p;
      const int ch = g32 * 32 + l32;
      const float2 c2 = *(const float2*)(cs + (long)bzs * 2048 + ch * 2);  // (csZ, csK)
      const long qbase = (ttile * 32 + g32) * 1024;
#pragma unroll
      for (int q = 0; q < 4; ++q) {
        const half4v qv = *(const half4v*)(Qsig + qbase + q * 256 + lane * 4);
#pragma unroll
        for (int rr = 0; rr < 4; ++rr) {
          const int reg = q * 4 + rr;
          const float num = c2.x + acc[mt][2 * p][reg] * 0.125f;
          const float den = c2.y + acc[mt][2 * p + 1][reg] * 0.125f;
          const int r = m0 + wm + mt * 32 + 4 * khalf + 8 * q + rr;
          const int R = bzs * 2048 + r;
          const long off = ((long)(R >> 7) * 16 + (ch >> 6)) * 8192 + frag_off(R & 127, ch & 63);
          OH[off] = (_Float16)((float)qv[rr] * num / den);
        }
      }
    }
  }
}

// ---------------- launch ----------------
extern "C" void kernel_launch(void* const* d_in, const int* in_sizes, int n_in, void* d_out,
                              int out_size, void* d_ws, size_t ws_size, hipStream_t stream) {
  const float* x = (const float*)d_in[0];
  const float* Wq = (const float*)d_in[1];
  const float* bq = (const float*)d_in[2];
  const float* Wk = (const float*)d_in[3];
  const float* bk = (const float*)d_in[4];
  const float* Wv = (const float*)d_in[5];
  const float* bv = (const float*)d_in[6];
  const float* Wo = (const float*)d_in[7];
  const float* bo = (const float*)d_in[8];
  const float* wb = (const float*)d_in[9];

  char* ws = (char*)d_ws;
  _Float16* x_h = (_Float16*)(ws + 0);              // 16 MB  (1024 f16 frag tiles)
  _Float16* WqkvT = (_Float16*)(ws + 16777216);     //  6 MB
  _Float16* WoT = (_Float16*)(ws + 23068672);       //  2 MB
  char* E8 = (char*)(ws + 25165824);                //  4 MB  (256 fp8 frag tiles)
  _Float16* Qsig = (_Float16*)(ws + 29360128);      // 16 MB  (C-frag tiles)
  char* Zt8 = (char*)(ws + 46137344);               // 16 MB  (fp8 frag tiles, 4 batches)
  _Float16* OutHead = (_Float16*)(ws + 62914560);   // 16 MB  (f16 frag tiles)
  float* cs = (float*)(ws + 79691776);              // 32 KB  (csZ,csK interleaved)

  hipMemsetAsync(cs, 0, 4 * 2048 * sizeof(float), stream);

  // prep: x tiles + weight tiles + E8 tiles
  prep_all<<<1792, 256, 0, stream>>>(x, wb, Wq, Wk, Wv, Wo, x_h, E8, WqkvT, WoT);

  // GEMM1: x @ [Wq|Wkv]; epilogue -> Qsig (C-frag), Zt8 (fp8), colsum atomics
  gemm_bt2<0><<<768, 512, 0, stream>>>(x_h, WqkvT, Qsig, bq, bk, bv, Zt8, cs);

  // GEMM2 (fp8 correction + rank-1): OutHead = Qsig*(csZ+E@Z)/(csK+E@eK)
  gemm2_fp8<<<256, 512, 0, stream>>>(E8, Zt8, OutHead, Qsig, cs);

  // GEMM3: out = OutHead @ Wo + bo (fp32)
  gemm_bt2<2><<<256, 512, 0, stream>>>(OutHead, WoT, d_out, bo, nullptr, nullptr, nullptr, nullptr);
}